// Round 2
// baseline (265.442 us; speedup 1.0000x reference)
//
#include <hip/hip_runtime.h>

typedef __attribute__((ext_vector_type(8))) short bf16x8;
typedef __attribute__((ext_vector_type(4))) float f32x4;
typedef unsigned short u16;

__device__ __forceinline__ float bf2f(u16 u) {
    return __builtin_bit_cast(float, ((unsigned int)u) << 16);
}
__device__ __forceinline__ u16 f2bf(float f) {
    unsigned int x = __builtin_bit_cast(unsigned int, f);
    x += 0x7FFFu + ((x >> 16) & 1u);   // RNE
    return (u16)(x >> 16);
}

// ---------------- weight convert: f32 -> bf16 for all four weight matrices ----------------
// sizes: qkv_w 196608, proj_w 65536, fc1_w 262144, fc2_w 262144 ; total 786432
__global__ __launch_bounds__(256) void cvt_kernel(
    const float* __restrict__ s0, const float* __restrict__ s1,
    const float* __restrict__ s2, const float* __restrict__ s3,
    u16* __restrict__ dst)
{
    const int i4 = (blockIdx.x * 256 + threadIdx.x) * 4;
    const float* src;
    int off;
    if      (i4 < 196608) { src = s0; off = i4; }
    else if (i4 < 262144) { src = s1; off = i4 - 196608; }
    else if (i4 < 524288) { src = s2; off = i4 - 262144; }
    else                  { src = s3; off = i4 - 524288; }
    float4 v = *(const float4*)(src + off);
    ushort4 o;
    o.x = f2bf(v.x); o.y = f2bf(v.y); o.z = f2bf(v.z); o.w = f2bf(v.w);
    *(ushort4*)(dst + i4) = o;
}

// ---------------- LayerNorm: one wave per token (C=256, 4 elems/lane), f32 in -> bf16 out ----
__global__ __launch_bounds__(256) void ln_kernel(
    const float* __restrict__ x, const float* __restrict__ g,
    const float* __restrict__ b, u16* __restrict__ y)
{
    const int tok  = blockIdx.x * 4 + (threadIdx.x >> 6);
    const int lane = threadIdx.x & 63;
    float4 v = *(const float4*)(x + (size_t)tok * 256 + lane * 4);
    float s  = v.x + v.y + v.z + v.w;
    float sq = v.x*v.x + v.y*v.y + v.z*v.z + v.w*v.w;
    #pragma unroll
    for (int off = 32; off; off >>= 1) {
        s  += __shfl_xor(s, off);
        sq += __shfl_xor(sq, off);
    }
    float mean = s * (1.0f / 256.0f);
    float var  = sq * (1.0f / 256.0f) - mean * mean;
    float rs   = rsqrtf(var + 1e-5f);
    float4 gv = *(const float4*)(g + lane * 4);
    float4 bv = *(const float4*)(b + lane * 4);
    ushort4 o;
    o.x = f2bf((v.x - mean) * rs * gv.x + bv.x);
    o.y = f2bf((v.y - mean) * rs * gv.y + bv.y);
    o.z = f2bf((v.z - mean) * rs * gv.z + bv.z);
    o.w = f2bf((v.w - mean) * rs * gv.w + bv.w);
    *(ushort4*)(y + (size_t)tok * 256 + lane * 4) = o;
}

// ---------------- GEMM: out[M][N] = A[M][K] @ W[N][K]^T + bias, epilogue ----------------
// EPI: 1 qkv (cols<256 scaled by dh^-0.5, bf16 out), 2 +residual (f32 res, f32 out),
//      3 exact gelu (bf16 out)
// Block: 256 thr = 4 waves; block tile 64 rows x 64 cols; wave tile 16x64.
template<int N, int K, int EPI>
__global__ __launch_bounds__(256) void gemm_kernel(
    const u16* __restrict__ A, const u16* __restrict__ W,
    const float* __restrict__ bias, const float* __restrict__ res,
    void* __restrict__ outv)
{
    const int lane  = threadIdx.x & 63;
    const int wave  = threadIdx.x >> 6;
    const int mbase = blockIdx.x * 64 + wave * 16;
    const int nbase = blockIdx.y * 64;
    const int lrow  = lane & 15;
    const int kq    = (lane >> 4) * 8;   // k offset of this lane's 8 contiguous elems

    f32x4 acc[4];
    #pragma unroll
    for (int t = 0; t < 4; ++t) acc[t] = (f32x4){0.f, 0.f, 0.f, 0.f};

    const u16* arow  = A + (size_t)(mbase + lrow) * K + kq;
    const u16* wbase = W + (size_t)(nbase + lrow) * K + kq;
    #pragma unroll 8
    for (int k0 = 0; k0 < K; k0 += 32) {
        bf16x8 afrag = *(const bf16x8*)(arow + k0);
        #pragma unroll
        for (int t = 0; t < 4; ++t) {
            bf16x8 bfrag = *(const bf16x8*)(wbase + (size_t)t * 16 * K + k0);
            acc[t] = __builtin_amdgcn_mfma_f32_16x16x32_bf16(afrag, bfrag, acc[t], 0, 0, 0);
        }
    }
    // C/D layout: col = lane&15, row = (lane>>4)*4 + r   [verified m89/m91]
    const int col   = lane & 15;
    const int rbase = (lane >> 4) * 4;
    #pragma unroll
    for (int t = 0; t < 4; ++t) {
        const int n  = nbase + t * 16 + col;
        const float bv = bias[n];
        #pragma unroll
        for (int r = 0; r < 4; ++r) {
            const int m = mbase + rbase + r;
            float v = acc[t][r] + bv;
            if (EPI == 1) {
                if (n < 256) v *= 0.1767766952966369f;  // 1/sqrt(32), q only
                ((u16*)outv)[(size_t)m * N + n] = f2bf(v);
            }
            if (EPI == 2) {
                v += res[(size_t)m * N + n];
                ((float*)outv)[(size_t)m * N + n] = v;
            }
            if (EPI == 3) {
                v = 0.5f * v * (1.0f + erff(v * 0.7071067811865475f));
                ((u16*)outv)[(size_t)m * N + n] = f2bf(v);
            }
        }
    }
}

// ---------------- Neighborhood attention: one wave per (token, head) ----------------
// qkv layout (bf16): [tok][3][NH][32]; q pre-scaled. rpb (f32): [NH][13][13].
__global__ __launch_bounds__(256) void attn_kernel(
    const u16* __restrict__ qkv, const float* __restrict__ rpb,
    u16* __restrict__ out)
{
    const int item = blockIdx.x * 4 + (threadIdx.x >> 6);
    const int lane = threadIdx.x & 63;
    const int head = item & 7;
    const int tok  = item >> 3;
    const int bb   = tok >> 12;
    const int i    = (tok >> 6) & 63;
    const int j    = tok & 63;

    // every lane broadcast-loads the full q vector (32 bf16)
    const u16* qp = qkv + (size_t)tok * 768 + head * 32;
    float q[32];
    #pragma unroll
    for (int d = 0; d < 32; ++d) q[d] = bf2f(qp[d]);

    // phase 1: lane = neighbor index (49 valid of 64)
    const int  n     = lane;
    const bool valid = n < 49;
    const int  kh = n / 7, kw = n % 7;
    const int  sh = min(max(i - 3, 0), 57);
    const int  sw = min(max(j - 3, 0), 57);
    const int  ih = sh + kh, iw = sw + kw;
    const int  tokn = valid ? (bb * 4096 + ih * 64 + iw) : tok;

    const u16* kp = qkv + (size_t)tokn * 768 + 256 + head * 32;
    float s = 0.f;
    #pragma unroll
    for (int d = 0; d < 32; ++d) s += q[d] * bf2f(kp[d]);
    const float bias = valid ? rpb[head * 169 + (ih - i + 6) * 13 + (iw - j + 6)] : 0.f;
    s = valid ? (s + bias) : -1e30f;

    float mx = s;
    #pragma unroll
    for (int off = 32; off; off >>= 1) mx = fmaxf(mx, __shfl_xor(mx, off));
    const float p = valid ? __expf(s - mx) : 0.f;
    float ps = p;
    #pragma unroll
    for (int off = 32; off; off >>= 1) ps += __shfl_xor(ps, off);
    const float pn = p / ps;

    // phase 2: lane = output dim d (two halves split the 49 neighbors)
    const int d    = lane & 31;
    const int half = lane >> 5;
    float acc = 0.f;
    #pragma unroll
    for (int t = 0; t < 25; ++t) {
        const int nn = half * 25 + t;
        if (nn < 49) {
            const float pv  = __shfl(pn, nn);
            const int   tkn = __shfl(tokn, nn);
            acc += pv * bf2f(qkv[(size_t)tkn * 768 + 512 + head * 32 + d]);
        }
    }
    acc += __shfl_xor(acc, 32);   // combine halves
    if (lane < 32) out[(size_t)tok * 256 + head * 32 + d] = f2bf(acc);
}

extern "C" void kernel_launch(void* const* d_in, const int* in_sizes, int n_in,
                              void* d_out, int out_size, void* d_ws, size_t ws_size,
                              hipStream_t stream)
{
    const float* x      = (const float*)d_in[0];
    const float* n1g    = (const float*)d_in[1];
    const float* n1b    = (const float*)d_in[2];
    const float* qkv_w  = (const float*)d_in[3];
    const float* qkv_b  = (const float*)d_in[4];
    const float* rpb    = (const float*)d_in[5];
    const float* proj_w = (const float*)d_in[6];
    const float* proj_b = (const float*)d_in[7];
    const float* n2g    = (const float*)d_in[8];
    const float* n2b    = (const float*)d_in[9];
    const float* fc1_w  = (const float*)d_in[10];
    const float* fc1_b  = (const float*)d_in[11];
    const float* fc2_w  = (const float*)d_in[12];
    const float* fc2_b  = (const float*)d_in[13];
    float* out = (float*)d_out;

    // workspace layout (byte offsets), ~35 MB total:
    //   [0,        1.5M)  weights bf16 (qkvW, projW, fc1W, fc2W)   live always
    //   [1.5M,     5.7M)  ln1 bf16  -> reused by attn bf16 after qkv gemm
    //   [5.7M,    18.3M)  qkv bf16  -> dead after attn; ln2 bf16 reuses [5.7M,9.9M)
    //   [9.9M,    26.7M)  hbuf bf16 (fc1 out)  (overlaps dead qkv tail)
    //   [26.7M,   35.1M)  x1 f32
    char* wsb = (char*)d_ws;
    u16*   wbf   = (u16*)wsb;                      // 786432 el
    u16*   qkvW  = wbf;
    u16*   projW = wbf + 196608;
    u16*   fc1W  = wbf + 262144;
    u16*   fc2W  = wbf + 524288;
    u16*   ln1   = (u16*)(wsb + 1572864);
    u16*   attn  = ln1;
    u16*   qkvB  = (u16*)(wsb + 5767168);
    u16*   ln2   = qkvB;
    u16*   hbuf  = (u16*)(wsb + 9961472);
    float* x1    = (float*)(wsb + 26738688);

    dim3 blk(256);
    cvt_kernel<<<768, blk, 0, stream>>>(qkv_w, proj_w, fc1_w, fc2_w, wbf);
    ln_kernel<<<2048, blk, 0, stream>>>(x, n1g, n1b, ln1);
    gemm_kernel<768, 256, 1><<<dim3(128, 12), blk, 0, stream>>>(ln1, qkvW, qkv_b, nullptr, qkvB);
    attn_kernel<<<16384, blk, 0, stream>>>(qkvB, rpb, attn);
    gemm_kernel<256, 256, 2><<<dim3(128, 4), blk, 0, stream>>>(attn, projW, proj_b, x, x1);
    ln_kernel<<<2048, blk, 0, stream>>>(x1, n2g, n2b, ln2);
    gemm_kernel<1024, 256, 3><<<dim3(128, 16), blk, 0, stream>>>(ln2, fc1W, fc1_b, nullptr, hbuf);
    gemm_kernel<256, 1024, 2><<<dim3(128, 4), blk, 0, stream>>>(hbuf, fc2W, fc2_b, x1, out);
}

// Round 3
// 190.400 us; speedup vs baseline: 1.3941x; 1.3941x over previous
//
#include <hip/hip_runtime.h>

typedef __attribute__((ext_vector_type(8))) short bf16x8;
typedef __attribute__((ext_vector_type(4))) float f32x4;
typedef unsigned short u16;

__device__ __forceinline__ float bf2f(u16 u) {
    return __builtin_bit_cast(float, ((unsigned int)u) << 16);
}
__device__ __forceinline__ u16 f2bf(float f) {
    unsigned int x = __builtin_bit_cast(unsigned int, f);
    x += 0x7FFFu + ((x >> 16) & 1u);   // RNE
    return (u16)(x >> 16);
}

typedef const __attribute__((address_space(1))) void* gas_t;
typedef __attribute__((address_space(3))) void* las_t;
__device__ __forceinline__ void load_lds16(const u16* g, u16* l) {
    __builtin_amdgcn_global_load_lds((gas_t)g, (las_t)l, 16, 0, 0);
}

// ---------------- weight convert: f32 -> bf16 for all four weight matrices ----------------
__global__ __launch_bounds__(256) void cvt_kernel(
    const float* __restrict__ s0, const float* __restrict__ s1,
    const float* __restrict__ s2, const float* __restrict__ s3,
    u16* __restrict__ dst)
{
    const int i4 = (blockIdx.x * 256 + threadIdx.x) * 4;
    const float* src;
    int off;
    if      (i4 < 196608) { src = s0; off = i4; }
    else if (i4 < 262144) { src = s1; off = i4 - 196608; }
    else if (i4 < 524288) { src = s2; off = i4 - 262144; }
    else                  { src = s3; off = i4 - 524288; }
    float4 v = *(const float4*)(src + off);
    ushort4 o;
    o.x = f2bf(v.x); o.y = f2bf(v.y); o.z = f2bf(v.z); o.w = f2bf(v.w);
    *(ushort4*)(dst + i4) = o;
}

// ---------------- LayerNorm: one wave per token (C=256), f32 in -> bf16 out ----------------
__global__ __launch_bounds__(256) void ln_kernel(
    const float* __restrict__ x, const float* __restrict__ g,
    const float* __restrict__ b, u16* __restrict__ y)
{
    const int tok  = blockIdx.x * 4 + (threadIdx.x >> 6);
    const int lane = threadIdx.x & 63;
    float4 v = *(const float4*)(x + (size_t)tok * 256 + lane * 4);
    float s  = v.x + v.y + v.z + v.w;
    float sq = v.x*v.x + v.y*v.y + v.z*v.z + v.w*v.w;
    #pragma unroll
    for (int off = 32; off; off >>= 1) {
        s  += __shfl_xor(s, off);
        sq += __shfl_xor(sq, off);
    }
    float mean = s * (1.0f / 256.0f);
    float var  = sq * (1.0f / 256.0f) - mean * mean;
    float rs   = rsqrtf(var + 1e-5f);
    float4 gv = *(const float4*)(g + lane * 4);
    float4 bv = *(const float4*)(b + lane * 4);
    ushort4 o;
    o.x = f2bf((v.x - mean) * rs * gv.x + bv.x);
    o.y = f2bf((v.y - mean) * rs * gv.y + bv.y);
    o.z = f2bf((v.z - mean) * rs * gv.z + bv.z);
    o.w = f2bf((v.w - mean) * rs * gv.w + bv.w);
    *(ushort4*)(y + (size_t)tok * 256 + lane * 4) = o;
}

// ---------------- LDS-tiled GEMM (m97 structure): out = A[M][K] @ W[N][K]^T + bias ------------
// Block: 256 thr = 4 waves, tile 128 x BN, BK=32, global_load_lds width 16.
// EPI: 1 qkv (cols<256 scaled, bf16 out), 2 +f32 residual (f32 out), 3 exact gelu (bf16 out)
template<int BN, int N, int K, int EPI>
__global__ __launch_bounds__(256) void gemm_lds(
    const u16* __restrict__ A, const u16* __restrict__ W,
    const float* __restrict__ bias, const float* __restrict__ res,
    void* __restrict__ outv)
{
    constexpr int NT = BN / 32;                 // n-tiles per wave (4 or 2)
    __shared__ u16 As[128 * 32];
    __shared__ u16 Bs[BN * 32];
    const int tid  = threadIdx.x;
    const int lane = tid & 63;
    const int wave = tid >> 6;
    const int m0   = blockIdx.x * 128;
    const int n0   = blockIdx.y * BN;
    const int wmb  = (wave >> 1) * 64;
    const int wnb  = (wave & 1) * (BN / 2);

    f32x4 acc[4][NT];
    #pragma unroll
    for (int mt = 0; mt < 4; ++mt)
        #pragma unroll
        for (int nt = 0; nt < NT; ++nt)
            acc[mt][nt] = (f32x4){0.f, 0.f, 0.f, 0.f};

    const int srow = tid >> 2;          // staging: 4 slots of 8 bf16 per 32-wide row
    const int skc  = (tid & 3) * 8;
    const int fr   = lane & 15;
    const int fk   = (lane >> 4) * 8;

    for (int k0 = 0; k0 < K; k0 += 32) {
        __syncthreads();
        load_lds16(A + (size_t)(m0 + srow) * K + k0 + skc,      As + tid * 8);
        load_lds16(A + (size_t)(m0 + 64 + srow) * K + k0 + skc, As + 2048 + tid * 8);
        load_lds16(W + (size_t)(n0 + srow) * K + k0 + skc,      Bs + tid * 8);
        if (BN == 128)
            load_lds16(W + (size_t)(n0 + 64 + srow) * K + k0 + skc, Bs + 2048 + tid * 8);
        __syncthreads();
        bf16x8 af[4], bf[NT];
        #pragma unroll
        for (int mt = 0; mt < 4; ++mt)
            af[mt] = *(const bf16x8*)(As + (wmb + mt * 16 + fr) * 32 + fk);
        #pragma unroll
        for (int nt = 0; nt < NT; ++nt)
            bf[nt] = *(const bf16x8*)(Bs + (wnb + nt * 16 + fr) * 32 + fk);
        #pragma unroll
        for (int mt = 0; mt < 4; ++mt)
            #pragma unroll
            for (int nt = 0; nt < NT; ++nt)
                acc[mt][nt] = __builtin_amdgcn_mfma_f32_16x16x32_bf16(af[mt], bf[nt], acc[mt][nt], 0, 0, 0);
    }

    // C/D layout: col = lane&15, row = (lane>>4)*4 + r
    const int col = lane & 15;
    const int rb  = (lane >> 4) * 4;
    #pragma unroll
    for (int nt = 0; nt < NT; ++nt) {
        const int n  = n0 + wnb + nt * 16 + col;
        const float bv = bias[n];
        #pragma unroll
        for (int mt = 0; mt < 4; ++mt) {
            #pragma unroll
            for (int r = 0; r < 4; ++r) {
                const int m = m0 + wmb + mt * 16 + rb + r;
                float v = acc[mt][nt][r] + bv;
                if (EPI == 1) {
                    if (n < 256) v *= 0.1767766952966369f;  // 1/sqrt(32), q only
                    ((u16*)outv)[(size_t)m * N + n] = f2bf(v);
                }
                if (EPI == 2) {
                    v += res[(size_t)m * N + n];
                    ((float*)outv)[(size_t)m * N + n] = v;
                }
                if (EPI == 3) {
                    v = 0.5f * v * (1.0f + erff(v * 0.7071067811865475f));
                    ((u16*)outv)[(size_t)m * N + n] = f2bf(v);
                }
            }
        }
    }
}

// ---------------- Neighborhood attention: one wave per (token, head) ----------------
// qkv layout (bf16): [tok][3][NH][32]; q pre-scaled. rpb (f32): [NH][13][13].
__global__ __launch_bounds__(256) void attn_kernel(
    const u16* __restrict__ qkv, const float* __restrict__ rpb,
    u16* __restrict__ out)
{
    const int item = blockIdx.x * 4 + (threadIdx.x >> 6);
    const int lane = threadIdx.x & 63;
    const int head = item & 7;
    const int tok  = item >> 3;
    const int bb   = tok >> 12;
    const int i    = (tok >> 6) & 63;
    const int j    = tok & 63;

    // broadcast-load full q vector: 4 x 16B
    const u16* qp = qkv + (size_t)tok * 768 + head * 32;
    float q[32];
    #pragma unroll
    for (int c = 0; c < 4; ++c) {
        bf16x8 v = *(const bf16x8*)(qp + c * 8);
        #pragma unroll
        for (int jj = 0; jj < 8; ++jj) q[c * 8 + jj] = bf2f((u16)v[jj]);
    }

    // phase 1: lane = neighbor index (49 valid of 64)
    const int  n     = lane;
    const bool valid = n < 49;
    const int  kh = n / 7, kw = n % 7;
    const int  sh = min(max(i - 3, 0), 57);
    const int  sw = min(max(j - 3, 0), 57);
    const int  ih = sh + kh, iw = sw + kw;
    const int  tokn = valid ? (bb * 4096 + ih * 64 + iw) : tok;

    const u16* kp = qkv + (size_t)tokn * 768 + 256 + head * 32;
    float s = 0.f;
    #pragma unroll
    for (int c = 0; c < 4; ++c) {
        bf16x8 v = *(const bf16x8*)(kp + c * 8);
        #pragma unroll
        for (int jj = 0; jj < 8; ++jj) s += q[c * 8 + jj] * bf2f((u16)v[jj]);
    }
    const float bias = valid ? rpb[head * 169 + (ih - i + 6) * 13 + (iw - j + 6)] : 0.f;
    s = valid ? (s + bias) : -1e30f;

    float mx = s;
    #pragma unroll
    for (int off = 32; off; off >>= 1) mx = fmaxf(mx, __shfl_xor(mx, off));
    const float p = valid ? __expf(s - mx) : 0.f;
    float ps = p;
    #pragma unroll
    for (int off = 32; off; off >>= 1) ps += __shfl_xor(ps, off);
    const float pn = p / ps;

    // phase 2: lane = dim pair (d2 of 16) x group (g of 4); groups split the 49 neighbors
    const int d2 = lane & 15;
    const int g  = lane >> 4;
    const u16* vbase = qkv;
    float a0 = 0.f, a1 = 0.f;
    #pragma unroll
    for (int t = 0; t < 13; ++t) {
        const int nn  = g + t * 4;
        const float pv  = __shfl(pn, nn & 63);
        const int   tkn = __shfl(tokn, nn & 63);
        if (nn < 49) {
            const unsigned int vv =
                *(const unsigned int*)(vbase + (size_t)tkn * 768 + 512 + head * 32 + d2 * 2);
            a0 += pv * bf2f((u16)(vv & 0xffffu));
            a1 += pv * bf2f((u16)(vv >> 16));
        }
    }
    a0 += __shfl_xor(a0, 16); a1 += __shfl_xor(a1, 16);
    a0 += __shfl_xor(a0, 32); a1 += __shfl_xor(a1, 32);
    if (lane < 16) {
        ushort2 o;
        o.x = f2bf(a0); o.y = f2bf(a1);
        *(ushort2*)(out + (size_t)tok * 256 + head * 32 + d2 * 2) = o;
    }
}

extern "C" void kernel_launch(void* const* d_in, const int* in_sizes, int n_in,
                              void* d_out, int out_size, void* d_ws, size_t ws_size,
                              hipStream_t stream)
{
    const float* x      = (const float*)d_in[0];
    const float* n1g    = (const float*)d_in[1];
    const float* n1b    = (const float*)d_in[2];
    const float* qkv_w  = (const float*)d_in[3];
    const float* qkv_b  = (const float*)d_in[4];
    const float* rpb    = (const float*)d_in[5];
    const float* proj_w = (const float*)d_in[6];
    const float* proj_b = (const float*)d_in[7];
    const float* n2g    = (const float*)d_in[8];
    const float* n2b    = (const float*)d_in[9];
    const float* fc1_w  = (const float*)d_in[10];
    const float* fc1_b  = (const float*)d_in[11];
    const float* fc2_w  = (const float*)d_in[12];
    const float* fc2_b  = (const float*)d_in[13];
    float* out = (float*)d_out;

    // workspace layout (byte offsets), ~35 MB total (aliased):
    char* wsb = (char*)d_ws;
    u16*   wbf   = (u16*)wsb;                      // 786432 el bf16 weights
    u16*   qkvW  = wbf;
    u16*   projW = wbf + 196608;
    u16*   fc1W  = wbf + 262144;
    u16*   fc2W  = wbf + 524288;
    u16*   ln1   = (u16*)(wsb + 1572864);          // 2M el
    u16*   attn  = ln1;                            // reuse after qkv gemm
    u16*   qkvB  = (u16*)(wsb + 5767168);          // 6M el
    u16*   ln2   = qkvB;                           // reuse after attn
    u16*   hbuf  = (u16*)(wsb + 9961472);          // 8M el
    float* x1    = (float*)(wsb + 26738688);       // 2M el f32

    dim3 blk(256);
    cvt_kernel<<<768, blk, 0, stream>>>(qkv_w, proj_w, fc1_w, fc2_w, wbf);
    ln_kernel<<<2048, blk, 0, stream>>>(x, n1g, n1b, ln1);
    gemm_lds<128, 768, 256, 1><<<dim3(64, 6), blk, 0, stream>>>(ln1, qkvW, qkv_b, nullptr, qkvB);
    attn_kernel<<<16384, blk, 0, stream>>>(qkvB, rpb, attn);
    gemm_lds<64, 256, 256, 2><<<dim3(64, 4), blk, 0, stream>>>(attn, projW, proj_b, x, x1);
    ln_kernel<<<2048, blk, 0, stream>>>(x1, n2g, n2b, ln2);
    gemm_lds<128, 1024, 256, 3><<<dim3(64, 8), blk, 0, stream>>>(ln2, fc1W, fc1_b, nullptr, hbuf);
    gemm_lds<64, 256, 1024, 2><<<dim3(64, 4), blk, 0, stream>>>(hbuf, fc2W, fc2_b, x1, out);
}

// Round 4
// 174.644 us; speedup vs baseline: 1.5199x; 1.0902x over previous
//
#include <hip/hip_runtime.h>

typedef __attribute__((ext_vector_type(8))) short bf16x8;
typedef __attribute__((ext_vector_type(4))) float f32x4;
typedef unsigned short u16;

__device__ __forceinline__ float bf2f(u16 u) {
    return __builtin_bit_cast(float, ((unsigned int)u) << 16);
}
__device__ __forceinline__ u16 f2bf(float f) {
    unsigned int x = __builtin_bit_cast(unsigned int, f);
    x += 0x7FFFu + ((x >> 16) & 1u);   // RNE
    return (u16)(x >> 16);
}

typedef const __attribute__((address_space(1))) void* gas_t;
typedef __attribute__((address_space(3))) void* las_t;
__device__ __forceinline__ void load_lds16(const u16* g, u16* l) {
    __builtin_amdgcn_global_load_lds((gas_t)g, (las_t)l, 16, 0, 0);
}

// ---------------- weight convert: f32 -> bf16 for all four weight matrices ----------------
__global__ __launch_bounds__(256) void cvt_kernel(
    const float* __restrict__ s0, const float* __restrict__ s1,
    const float* __restrict__ s2, const float* __restrict__ s3,
    u16* __restrict__ dst)
{
    const int i4 = (blockIdx.x * 256 + threadIdx.x) * 4;
    const float* src;
    int off;
    if      (i4 < 196608) { src = s0; off = i4; }
    else if (i4 < 262144) { src = s1; off = i4 - 196608; }
    else if (i4 < 524288) { src = s2; off = i4 - 262144; }
    else                  { src = s3; off = i4 - 524288; }
    float4 v = *(const float4*)(src + off);
    ushort4 o;
    o.x = f2bf(v.x); o.y = f2bf(v.y); o.z = f2bf(v.z); o.w = f2bf(v.w);
    *(ushort4*)(dst + i4) = o;
}

// ---------------- LayerNorm: one wave per token (C=256), f32 in -> bf16 out ----------------
__global__ __launch_bounds__(256) void ln_kernel(
    const float* __restrict__ x, const float* __restrict__ g,
    const float* __restrict__ b, u16* __restrict__ y)
{
    const int tok  = blockIdx.x * 4 + (threadIdx.x >> 6);
    const int lane = threadIdx.x & 63;
    float4 v = *(const float4*)(x + (size_t)tok * 256 + lane * 4);
    float s  = v.x + v.y + v.z + v.w;
    float sq = v.x*v.x + v.y*v.y + v.z*v.z + v.w*v.w;
    #pragma unroll
    for (int off = 32; off; off >>= 1) {
        s  += __shfl_xor(s, off);
        sq += __shfl_xor(sq, off);
    }
    float mean = s * (1.0f / 256.0f);
    float var  = sq * (1.0f / 256.0f) - mean * mean;
    float rs   = rsqrtf(var + 1e-5f);
    float4 gv = *(const float4*)(g + lane * 4);
    float4 bv = *(const float4*)(b + lane * 4);
    ushort4 o;
    o.x = f2bf((v.x - mean) * rs * gv.x + bv.x);
    o.y = f2bf((v.y - mean) * rs * gv.y + bv.y);
    o.z = f2bf((v.z - mean) * rs * gv.z + bv.z);
    o.w = f2bf((v.w - mean) * rs * gv.w + bv.w);
    *(ushort4*)(y + (size_t)tok * 256 + lane * 4) = o;
}

// ---------------- LDS-tiled GEMM (m97 structure): out = A[M][K] @ W[N][K]^T + bias ------------
// Block: 256 thr = 4 waves, tile 128 x BN, BK=32, global_load_lds width 16.
// EPI: 1 qkv (cols<256 scaled, bf16 out), 2 +f32 residual (f32 out), 3 exact gelu (bf16 out)
template<int BN, int N, int K, int EPI>
__global__ __launch_bounds__(256) void gemm_lds(
    const u16* __restrict__ A, const u16* __restrict__ W,
    const float* __restrict__ bias, const float* __restrict__ res,
    void* __restrict__ outv)
{
    constexpr int NT = BN / 32;                 // n-tiles per wave (4 or 2)
    __shared__ u16 As[128 * 32];
    __shared__ u16 Bs[BN * 32];
    const int tid  = threadIdx.x;
    const int lane = tid & 63;
    const int wave = tid >> 6;
    const int m0   = blockIdx.x * 128;
    const int n0   = blockIdx.y * BN;
    const int wmb  = (wave >> 1) * 64;
    const int wnb  = (wave & 1) * (BN / 2);

    f32x4 acc[4][NT];
    #pragma unroll
    for (int mt = 0; mt < 4; ++mt)
        #pragma unroll
        for (int nt = 0; nt < NT; ++nt)
            acc[mt][nt] = (f32x4){0.f, 0.f, 0.f, 0.f};

    const int srow = tid >> 2;          // staging: 4 slots of 8 bf16 per 32-wide row
    const int skc  = (tid & 3) * 8;
    const int fr   = lane & 15;
    const int fk   = (lane >> 4) * 8;

    for (int k0 = 0; k0 < K; k0 += 32) {
        __syncthreads();
        load_lds16(A + (size_t)(m0 + srow) * K + k0 + skc,      As + tid * 8);
        load_lds16(A + (size_t)(m0 + 64 + srow) * K + k0 + skc, As + 2048 + tid * 8);
        load_lds16(W + (size_t)(n0 + srow) * K + k0 + skc,      Bs + tid * 8);
        if (BN == 128)
            load_lds16(W + (size_t)(n0 + 64 + srow) * K + k0 + skc, Bs + 2048 + tid * 8);
        __syncthreads();
        bf16x8 af[4], bf[NT];
        #pragma unroll
        for (int mt = 0; mt < 4; ++mt)
            af[mt] = *(const bf16x8*)(As + (wmb + mt * 16 + fr) * 32 + fk);
        #pragma unroll
        for (int nt = 0; nt < NT; ++nt)
            bf[nt] = *(const bf16x8*)(Bs + (wnb + nt * 16 + fr) * 32 + fk);
        #pragma unroll
        for (int mt = 0; mt < 4; ++mt)
            #pragma unroll
            for (int nt = 0; nt < NT; ++nt)
                acc[mt][nt] = __builtin_amdgcn_mfma_f32_16x16x32_bf16(af[mt], bf[nt], acc[mt][nt], 0, 0, 0);
    }

    // C/D layout: col = lane&15, row = (lane>>4)*4 + r
    const int col = lane & 15;
    const int rb  = (lane >> 4) * 4;
    #pragma unroll
    for (int nt = 0; nt < NT; ++nt) {
        const int n  = n0 + wnb + nt * 16 + col;
        const float bv = bias[n];
        #pragma unroll
        for (int mt = 0; mt < 4; ++mt) {
            #pragma unroll
            for (int r = 0; r < 4; ++r) {
                const int m = m0 + wmb + mt * 16 + rb + r;
                float v = acc[mt][nt][r] + bv;
                if (EPI == 1) {
                    if (n < 256) v *= 0.1767766952966369f;  // 1/sqrt(32), q only
                    ((u16*)outv)[(size_t)m * N + n] = f2bf(v);
                }
                if (EPI == 2) {
                    v += res[(size_t)m * N + n];
                    ((float*)outv)[(size_t)m * N + n] = v;
                }
                if (EPI == 3) {
                    v = 0.5f * v * (1.0f + erff(v * 0.7071067811865475f));
                    ((u16*)outv)[(size_t)m * N + n] = f2bf(v);
                }
            }
        }
    }
}

// ---------------- Neighborhood attention, LDS-staged tile version ----------------
// Block = 4x4 spatial tile x all 8 heads. 512 blocks, 256 threads.
// qkv (bf16): [tok][3][8][32], q pre-scaled. rpb f32 [8][13][13]. out bf16 [tok][256].
// LDS kv: [halo_tok(100)][32 k | 32 v], 16B chunks XOR-swizzled: chunk c of token t
// lives at slot t*8 + (c ^ (t&7)) to spread the 128B row stride across banks.
__global__ __launch_bounds__(256, 2) void attn_tile_kernel(
    const u16* __restrict__ qkv, const float* __restrict__ rpb,
    u16* __restrict__ out)
{
    __shared__ u16   kv[100 * 64];
    __shared__ u16   qs[16 * 32];
    __shared__ float probs[16 * 66];

    const int tid  = threadIdx.x;
    const int bb   = blockIdx.x >> 8;
    const int rem  = blockIdx.x & 255;
    const int ti0  = (rem >> 4) << 2;
    const int tj0  = (rem & 15) << 2;
    const int oh   = min(max(ti0 - 3, 0), 54);
    const int ow   = min(max(tj0 - 3, 0), 54);
    const int tokbase = bb * 4096;

    // h-independent staging source offsets (elements)
    int off_kv[4];
    #pragma unroll
    for (int r = 0; r < 4; ++r) {
        const int s  = r * 256 + tid;        // LDS chunk slot
        const int t  = s >> 3;               // halo token 0..99
        const int cs = s & 7;
        const int c  = cs ^ (t & 7);         // global chunk this slot receives
        const int tr = t / 10, tc = t - tr * 10;
        const int tokg = tokbase + (oh + tr) * 64 + (ow + tc);
        // k chunks 0..3 at +256, v chunks 4..7 at +512 (head offset added later)
        off_kv[r] = tokg * 768 + 256 + ((c & 4) << 6) + (c & 3) * 8;
    }
    const int tq   = tid >> 2;               // q staging (first 64 threads)
    const int qoff = (tokbase + (ti0 + (tq >> 2)) * 64 + (tj0 + (tq & 3))) * 768
                   + (tid & 3) * 8;

    // compute-phase constants: thread = (token 0..15, part 0..15)
    const int token = tid >> 4;
    const int part  = tid & 15;
    const int li = token >> 2, lj = token & 3;
    const int i  = ti0 + li,   j  = tj0 + lj;
    const int sh = min(max(i - 3, 0), 57);
    const int sw = min(max(j - 3, 0), 57);
    const int rowbase  = (sh - oh) * 10 + (sw - ow);
    const int rb_const = (sh - i + 6) * 13 + (sw - j + 6);
    const size_t outbase = (size_t)(tokbase + i * 64 + j) * 256 + part * 2;

    for (int h = 0; h < 8; ++h) {
        __syncthreads();                     // previous head's LDS reads done
        const int hoff = h * 32;
        #pragma unroll
        for (int r = 0; r < 3; ++r)
            load_lds16(qkv + off_kv[r] + hoff, kv + (r * 256 + tid) * 8);
        if (tid < 32)
            load_lds16(qkv + off_kv[3] + hoff, kv + (768 + tid) * 8);
        if (tid < 64)
            load_lds16(qkv + qoff + hoff, qs + tid * 8);
        __syncthreads();

        // q broadcast (16 lanes of a token read the same rows)
        float qv[32];
        #pragma unroll
        for (int c = 0; c < 4; ++c) {
            bf16x8 v = *(const bf16x8*)(qs + token * 32 + c * 8);
            #pragma unroll
            for (int e = 0; e < 8; ++e) qv[c * 8 + e] = bf2f((u16)v[e]);
        }

        // scores: neighbor n = part + 16*sidx
        float sc[4];
        #pragma unroll
        for (int sidx = 0; sidx < 4; ++sidx) {
            const int n = part + sidx * 16;
            if (n < 49) {
                const int kh = n / 7, kw = n - (n / 7) * 7;
                const int hidx = rowbase + kh * 10 + kw;
                float acc = rpb[h * 169 + rb_const + kh * 13 + kw];
                #pragma unroll
                for (int c = 0; c < 4; ++c) {
                    const int slot = (hidx << 3) + (c ^ (hidx & 7));
                    bf16x8 kk = *(const bf16x8*)(kv + slot * 8);
                    #pragma unroll
                    for (int e = 0; e < 8; ++e)
                        acc += qv[c * 8 + e] * bf2f((u16)kk[e]);
                }
                sc[sidx] = acc;
            } else {
                sc[sidx] = -1e30f;
            }
        }
        // softmax across the token's 16 parts (49 valid scores)
        float mx = fmaxf(fmaxf(sc[0], sc[1]), fmaxf(sc[2], sc[3]));
        #pragma unroll
        for (int off = 1; off < 16; off <<= 1) mx = fmaxf(mx, __shfl_xor(mx, off));
        float ex[4], ssum = 0.f;
        #pragma unroll
        for (int sidx = 0; sidx < 4; ++sidx) {
            ex[sidx] = __expf(sc[sidx] - mx);   // underflows to 0 for invalid
            ssum += ex[sidx];
        }
        #pragma unroll
        for (int off = 1; off < 16; off <<= 1) ssum += __shfl_xor(ssum, off);
        const float inv = 1.0f / ssum;
        #pragma unroll
        for (int sidx = 0; sidx < 4; ++sidx)
            probs[token * 66 + part + sidx * 16] = ex[sidx] * inv;
        __syncthreads();

        // PV: part p accumulates dims 2p, 2p+1 over all 49 neighbors
        float o0 = 0.f, o1 = 0.f;
        const int vchunk = 4 + (part >> 2);
        const int vsub   = (part & 3) * 2;
        #pragma unroll
        for (int kh = 0; kh < 7; ++kh) {
            #pragma unroll
            for (int kw = 0; kw < 7; ++kw) {
                const int n    = kh * 7 + kw;
                const int hidx = rowbase + kh * 10 + kw;
                const float p  = probs[token * 66 + n];
                const int slot = (hidx << 3) + (vchunk ^ (hidx & 7));
                const unsigned int vv = *(const unsigned int*)(kv + slot * 8 + vsub);
                o0 += p * bf2f((u16)(vv & 0xffffu));
                o1 += p * bf2f((u16)(vv >> 16));
            }
        }
        ushort2 ov;
        ov.x = f2bf(o0); ov.y = f2bf(o1);
        *(ushort2*)(out + outbase + hoff) = ov;
    }
}

extern "C" void kernel_launch(void* const* d_in, const int* in_sizes, int n_in,
                              void* d_out, int out_size, void* d_ws, size_t ws_size,
                              hipStream_t stream)
{
    const float* x      = (const float*)d_in[0];
    const float* n1g    = (const float*)d_in[1];
    const float* n1b    = (const float*)d_in[2];
    const float* qkv_w  = (const float*)d_in[3];
    const float* qkv_b  = (const float*)d_in[4];
    const float* rpb    = (const float*)d_in[5];
    const float* proj_w = (const float*)d_in[6];
    const float* proj_b = (const float*)d_in[7];
    const float* n2g    = (const float*)d_in[8];
    const float* n2b    = (const float*)d_in[9];
    const float* fc1_w  = (const float*)d_in[10];
    const float* fc1_b  = (const float*)d_in[11];
    const float* fc2_w  = (const float*)d_in[12];
    const float* fc2_b  = (const float*)d_in[13];
    float* out = (float*)d_out;

    // workspace layout (byte offsets), ~35 MB total (aliased):
    char* wsb = (char*)d_ws;
    u16*   wbf   = (u16*)wsb;                      // 786432 el bf16 weights
    u16*   qkvW  = wbf;
    u16*   projW = wbf + 196608;
    u16*   fc1W  = wbf + 262144;
    u16*   fc2W  = wbf + 524288;
    u16*   ln1   = (u16*)(wsb + 1572864);          // 2M el
    u16*   attn  = ln1;                            // reuse after qkv gemm
    u16*   qkvB  = (u16*)(wsb + 5767168);          // 6M el
    u16*   ln2   = qkvB;                           // reuse after attn
    u16*   hbuf  = (u16*)(wsb + 9961472);          // 8M el
    float* x1    = (float*)(wsb + 26738688);       // 2M el f32

    dim3 blk(256);
    cvt_kernel<<<768, blk, 0, stream>>>(qkv_w, proj_w, fc1_w, fc2_w, wbf);
    ln_kernel<<<2048, blk, 0, stream>>>(x, n1g, n1b, ln1);
    gemm_lds<128, 768, 256, 1><<<dim3(64, 6), blk, 0, stream>>>(ln1, qkvW, qkv_b, nullptr, qkvB);
    attn_tile_kernel<<<512, blk, 0, stream>>>(qkvB, rpb, attn);
    gemm_lds<64, 256, 256, 2><<<dim3(64, 4), blk, 0, stream>>>(attn, projW, proj_b, x, x1);
    ln_kernel<<<2048, blk, 0, stream>>>(x1, n2g, n2b, ln2);
    gemm_lds<128, 1024, 256, 3><<<dim3(64, 8), blk, 0, stream>>>(ln2, fc1W, fc1_b, nullptr, hbuf);
    gemm_lds<64, 256, 1024, 2><<<dim3(64, 4), blk, 0, stream>>>(hbuf, fc2W, fc2_b, x1, out);
}

// Round 5
// 165.111 us; speedup vs baseline: 1.6077x; 1.0577x over previous
//
#include <hip/hip_runtime.h>

typedef __attribute__((ext_vector_type(8))) short bf16x8;
typedef __attribute__((ext_vector_type(4))) float f32x4;
typedef unsigned short u16;

__device__ __forceinline__ float bf2f(u16 u) {
    return __builtin_bit_cast(float, ((unsigned int)u) << 16);
}
__device__ __forceinline__ u16 f2bf(float f) {
    unsigned int x = __builtin_bit_cast(unsigned int, f);
    x += 0x7FFFu + ((x >> 16) & 1u);   // RNE
    return (u16)(x >> 16);
}

typedef const __attribute__((address_space(1))) void* gas_t;
typedef __attribute__((address_space(3))) void* las_t;
__device__ __forceinline__ void load_lds16(const u16* g, u16* l) {
    __builtin_amdgcn_global_load_lds((gas_t)g, (las_t)l, 16, 0, 0);
}

// ---------------- weight convert: f32 -> bf16 for all four weight matrices ----------------
__global__ __launch_bounds__(256) void cvt_kernel(
    const float* __restrict__ s0, const float* __restrict__ s1,
    const float* __restrict__ s2, const float* __restrict__ s3,
    u16* __restrict__ dst)
{
    const int i4 = (blockIdx.x * 256 + threadIdx.x) * 4;
    const float* src;
    int off;
    if      (i4 < 196608) { src = s0; off = i4; }
    else if (i4 < 262144) { src = s1; off = i4 - 196608; }
    else if (i4 < 524288) { src = s2; off = i4 - 262144; }
    else                  { src = s3; off = i4 - 524288; }
    float4 v = *(const float4*)(src + off);
    ushort4 o;
    o.x = f2bf(v.x); o.y = f2bf(v.y); o.z = f2bf(v.z); o.w = f2bf(v.w);
    *(ushort4*)(dst + i4) = o;
}

// ---------------- LayerNorm: one wave per token (C=256), f32 in -> bf16 out ----------------
__global__ __launch_bounds__(256) void ln_kernel(
    const float* __restrict__ x, const float* __restrict__ g,
    const float* __restrict__ b, u16* __restrict__ y)
{
    const int tok  = blockIdx.x * 4 + (threadIdx.x >> 6);
    const int lane = threadIdx.x & 63;
    float4 v = *(const float4*)(x + (size_t)tok * 256 + lane * 4);
    float s  = v.x + v.y + v.z + v.w;
    float sq = v.x*v.x + v.y*v.y + v.z*v.z + v.w*v.w;
    #pragma unroll
    for (int off = 32; off; off >>= 1) {
        s  += __shfl_xor(s, off);
        sq += __shfl_xor(sq, off);
    }
    float mean = s * (1.0f / 256.0f);
    float var  = sq * (1.0f / 256.0f) - mean * mean;
    float rs   = rsqrtf(var + 1e-5f);
    float4 gv = *(const float4*)(g + lane * 4);
    float4 bv = *(const float4*)(b + lane * 4);
    ushort4 o;
    o.x = f2bf((v.x - mean) * rs * gv.x + bv.x);
    o.y = f2bf((v.y - mean) * rs * gv.y + bv.y);
    o.z = f2bf((v.z - mean) * rs * gv.z + bv.z);
    o.w = f2bf((v.w - mean) * rs * gv.w + bv.w);
    *(ushort4*)(y + (size_t)tok * 256 + lane * 4) = o;
}

// ---------------- 64x64-tile GEMM, BK=64, XOR-swizzled LDS: out = A@W^T + bias ----------------
// Grid (M/64, N/64), 256 thr = 4 waves, wave = 32x32 quadrant. 16 KB LDS -> many blocks/CU.
// LDS layout: row-major [64][64], 16B chunk c of row r stored at chunk (c ^ (r&7))
// -> fragment reads spread across all 32 banks (2-way = free), staging stays
//    wave-contiguous (global_load_lds constraint), sources per-lane swizzled.
// EPI: 1 qkv (cols<256 scaled, bf16 out), 2 +f32 residual (f32 out), 3 exact gelu (bf16 out)
template<int N, int K, int EPI>
__global__ __launch_bounds__(256) void gemm64(
    const u16* __restrict__ A, const u16* __restrict__ W,
    const float* __restrict__ bias, const float* __restrict__ res,
    void* __restrict__ outv)
{
    __shared__ u16 As[64 * 64];
    __shared__ u16 Bs[64 * 64];
    const int tid  = threadIdx.x;
    const int lane = tid & 63;
    const int wave = tid >> 6;
    const int m0   = blockIdx.x * 64;
    const int n0   = blockIdx.y * 64;
    const int wm0  = (wave >> 1) * 32;
    const int wn0  = (wave & 1) * 32;

    f32x4 acc[2][2];
    #pragma unroll
    for (int mt = 0; mt < 2; ++mt)
        #pragma unroll
        for (int nt = 0; nt < 2; ++nt)
            acc[mt][nt] = (f32x4){0.f, 0.f, 0.f, 0.f};

    // staging map: slot s = r*256+tid -> row s>>3, phys chunk s&7, global chunk (s&7)^(row&7)
    int soff[2];
    #pragma unroll
    for (int r = 0; r < 2; ++r) {
        const int s   = r * 256 + tid;
        const int row = s >> 3;
        const int c   = (s & 7) ^ (row & 7);
        soff[r] = row * K + c * 8;
    }
    const int fr = lane & 15;
    const int fc = lane >> 4;           // logical chunk sub-index within kstep

    for (int k0 = 0; k0 < K; k0 += 64) {
        __syncthreads();
        #pragma unroll
        for (int r = 0; r < 2; ++r) {
            load_lds16(A + (size_t)m0 * K + k0 + soff[r], As + (r * 256 + tid) * 8);
            load_lds16(W + (size_t)n0 * K + k0 + soff[r], Bs + (r * 256 + tid) * 8);
        }
        __syncthreads();
        #pragma unroll
        for (int ks = 0; ks < 2; ++ks) {
            bf16x8 af[2], bw[2];
            #pragma unroll
            for (int mt = 0; mt < 2; ++mt) {
                const int rr   = wm0 + mt * 16 + fr;
                const int phys = (ks * 4 + fc) ^ (rr & 7);
                af[mt] = *(const bf16x8*)(As + rr * 64 + phys * 8);
            }
            #pragma unroll
            for (int nt = 0; nt < 2; ++nt) {
                const int rr   = wn0 + nt * 16 + fr;
                const int phys = (ks * 4 + fc) ^ (rr & 7);
                bw[nt] = *(const bf16x8*)(Bs + rr * 64 + phys * 8);
            }
            #pragma unroll
            for (int mt = 0; mt < 2; ++mt)
                #pragma unroll
                for (int nt = 0; nt < 2; ++nt)
                    acc[mt][nt] = __builtin_amdgcn_mfma_f32_16x16x32_bf16(af[mt], bw[nt], acc[mt][nt], 0, 0, 0);
        }
    }

    // C/D layout: col = lane&15, row = (lane>>4)*4 + r
    const int col = lane & 15;
    const int rb  = (lane >> 4) * 4;
    #pragma unroll
    for (int nt = 0; nt < 2; ++nt) {
        const int n  = n0 + wn0 + nt * 16 + col;
        const float bv = bias[n];
        #pragma unroll
        for (int mt = 0; mt < 2; ++mt) {
            #pragma unroll
            for (int r = 0; r < 4; ++r) {
                const int m = m0 + wm0 + mt * 16 + rb + r;
                float v = acc[mt][nt][r] + bv;
                if (EPI == 1) {
                    if (n < 256) v *= 0.1767766952966369f;  // 1/sqrt(32), q only
                    ((u16*)outv)[(size_t)m * N + n] = f2bf(v);
                }
                if (EPI == 2) {
                    v += res[(size_t)m * N + n];
                    ((float*)outv)[(size_t)m * N + n] = v;
                }
                if (EPI == 3) {
                    v = 0.5f * v * (1.0f + erff(v * 0.7071067811865475f));
                    ((u16*)outv)[(size_t)m * N + n] = f2bf(v);
                }
            }
        }
    }
}

// ---------------- Neighborhood attention, LDS-staged tile version ----------------
// Block = 4x4 spatial tile x all 8 heads. 512 blocks, 256 threads.
__global__ __launch_bounds__(256, 2) void attn_tile_kernel(
    const u16* __restrict__ qkv, const float* __restrict__ rpb,
    u16* __restrict__ out)
{
    __shared__ u16   kv[100 * 64];
    __shared__ u16   qs[16 * 32];
    __shared__ float probs[16 * 66];

    const int tid  = threadIdx.x;
    const int bb   = blockIdx.x >> 8;
    const int rem  = blockIdx.x & 255;
    const int ti0  = (rem >> 4) << 2;
    const int tj0  = (rem & 15) << 2;
    const int oh   = min(max(ti0 - 3, 0), 54);
    const int ow   = min(max(tj0 - 3, 0), 54);
    const int tokbase = bb * 4096;

    int off_kv[4];
    #pragma unroll
    for (int r = 0; r < 4; ++r) {
        const int s  = r * 256 + tid;
        const int t  = s >> 3;
        const int cs = s & 7;
        const int c  = cs ^ (t & 7);
        const int tr = t / 10, tc = t - tr * 10;
        const int tokg = tokbase + (oh + tr) * 64 + (ow + tc);
        off_kv[r] = tokg * 768 + 256 + ((c & 4) << 6) + (c & 3) * 8;
    }
    const int tq   = tid >> 2;
    const int qoff = (tokbase + (ti0 + (tq >> 2)) * 64 + (tj0 + (tq & 3))) * 768
                   + (tid & 3) * 8;

    const int token = tid >> 4;
    const int part  = tid & 15;
    const int li = token >> 2, lj = token & 3;
    const int i  = ti0 + li,   j  = tj0 + lj;
    const int sh = min(max(i - 3, 0), 57);
    const int sw = min(max(j - 3, 0), 57);
    const int rowbase  = (sh - oh) * 10 + (sw - ow);
    const int rb_const = (sh - i + 6) * 13 + (sw - j + 6);
    const size_t outbase = (size_t)(tokbase + i * 64 + j) * 256 + part * 2;

    for (int h = 0; h < 8; ++h) {
        __syncthreads();
        const int hoff = h * 32;
        #pragma unroll
        for (int r = 0; r < 3; ++r)
            load_lds16(qkv + off_kv[r] + hoff, kv + (r * 256 + tid) * 8);
        if (tid < 32)
            load_lds16(qkv + off_kv[3] + hoff, kv + (768 + tid) * 8);
        if (tid < 64)
            load_lds16(qkv + qoff + hoff, qs + tid * 8);
        __syncthreads();

        float qv[32];
        #pragma unroll
        for (int c = 0; c < 4; ++c) {
            bf16x8 v = *(const bf16x8*)(qs + token * 32 + c * 8);
            #pragma unroll
            for (int e = 0; e < 8; ++e) qv[c * 8 + e] = bf2f((u16)v[e]);
        }

        float sc[4];
        #pragma unroll
        for (int sidx = 0; sidx < 4; ++sidx) {
            const int n = part + sidx * 16;
            if (n < 49) {
                const int kh = n / 7, kw = n - (n / 7) * 7;
                const int hidx = rowbase + kh * 10 + kw;
                float acc = rpb[h * 169 + rb_const + kh * 13 + kw];
                #pragma unroll
                for (int c = 0; c < 4; ++c) {
                    const int slot = (hidx << 3) + (c ^ (hidx & 7));
                    bf16x8 kk = *(const bf16x8*)(kv + slot * 8);
                    #pragma unroll
                    for (int e = 0; e < 8; ++e)
                        acc += qv[c * 8 + e] * bf2f((u16)kk[e]);
                }
                sc[sidx] = acc;
            } else {
                sc[sidx] = -1e30f;
            }
        }
        float mx = fmaxf(fmaxf(sc[0], sc[1]), fmaxf(sc[2], sc[3]));
        #pragma unroll
        for (int off = 1; off < 16; off <<= 1) mx = fmaxf(mx, __shfl_xor(mx, off));
        float ex[4], ssum = 0.f;
        #pragma unroll
        for (int sidx = 0; sidx < 4; ++sidx) {
            ex[sidx] = __expf(sc[sidx] - mx);
            ssum += ex[sidx];
        }
        #pragma unroll
        for (int off = 1; off < 16; off <<= 1) ssum += __shfl_xor(ssum, off);
        const float inv = 1.0f / ssum;
        #pragma unroll
        for (int sidx = 0; sidx < 4; ++sidx)
            probs[token * 66 + part + sidx * 16] = ex[sidx] * inv;
        __syncthreads();

        float o0 = 0.f, o1 = 0.f;
        const int vchunk = 4 + (part >> 2);
        const int vsub   = (part & 3) * 2;
        #pragma unroll
        for (int kh = 0; kh < 7; ++kh) {
            #pragma unroll
            for (int kw = 0; kw < 7; ++kw) {
                const int n    = kh * 7 + kw;
                const int hidx = rowbase + kh * 10 + kw;
                const float p  = probs[token * 66 + n];
                const int slot = (hidx << 3) + (vchunk ^ (hidx & 7));
                const unsigned int vv = *(const unsigned int*)(kv + slot * 8 + vsub);
                o0 += p * bf2f((u16)(vv & 0xffffu));
                o1 += p * bf2f((u16)(vv >> 16));
            }
        }
        ushort2 ov;
        ov.x = f2bf(o0); ov.y = f2bf(o1);
        *(ushort2*)(out + outbase + hoff) = ov;
    }
}

extern "C" void kernel_launch(void* const* d_in, const int* in_sizes, int n_in,
                              void* d_out, int out_size, void* d_ws, size_t ws_size,
                              hipStream_t stream)
{
    const float* x      = (const float*)d_in[0];
    const float* n1g    = (const float*)d_in[1];
    const float* n1b    = (const float*)d_in[2];
    const float* qkv_w  = (const float*)d_in[3];
    const float* qkv_b  = (const float*)d_in[4];
    const float* rpb    = (const float*)d_in[5];
    const float* proj_w = (const float*)d_in[6];
    const float* proj_b = (const float*)d_in[7];
    const float* n2g    = (const float*)d_in[8];
    const float* n2b    = (const float*)d_in[9];
    const float* fc1_w  = (const float*)d_in[10];
    const float* fc1_b  = (const float*)d_in[11];
    const float* fc2_w  = (const float*)d_in[12];
    const float* fc2_b  = (const float*)d_in[13];
    float* out = (float*)d_out;

    char* wsb = (char*)d_ws;
    u16*   wbf   = (u16*)wsb;                      // 786432 el bf16 weights
    u16*   qkvW  = wbf;
    u16*   projW = wbf + 196608;
    u16*   fc1W  = wbf + 262144;
    u16*   fc2W  = wbf + 524288;
    u16*   ln1   = (u16*)(wsb + 1572864);          // 2M el
    u16*   attn  = ln1;                            // reuse after qkv gemm
    u16*   qkvB  = (u16*)(wsb + 5767168);          // 6M el
    u16*   ln2   = qkvB;                           // reuse after attn
    u16*   hbuf  = (u16*)(wsb + 9961472);          // 8M el
    float* x1    = (float*)(wsb + 26738688);       // 2M el f32

    dim3 blk(256);
    cvt_kernel<<<768, blk, 0, stream>>>(qkv_w, proj_w, fc1_w, fc2_w, wbf);
    ln_kernel<<<2048, blk, 0, stream>>>(x, n1g, n1b, ln1);
    gemm64<768, 256, 1><<<dim3(128, 12), blk, 0, stream>>>(ln1, qkvW, qkv_b, nullptr, qkvB);
    attn_tile_kernel<<<512, blk, 0, stream>>>(qkvB, rpb, attn);
    gemm64<256, 256, 2><<<dim3(128, 4), blk, 0, stream>>>(attn, projW, proj_b, x, x1);
    ln_kernel<<<2048, blk, 0, stream>>>(x1, n2g, n2b, ln2);
    gemm64<1024, 256, 3><<<dim3(128, 16), blk, 0, stream>>>(ln2, fc1W, fc1_b, nullptr, hbuf);
    gemm64<256, 1024, 2><<<dim3(128, 4), blk, 0, stream>>>(hbuf, fc2W, fc2_b, x1, out);
}